// Round 6
// baseline (102.035 us; speedup 1.0000x reference)
//
#include <hip/hip_runtime.h>
#include <hip/hip_bf16.h>

#define BATCH 128
#define NOUT  256
#define MB    8
#define IN    512

#define THREADS 256
#define TI 32            // i-tile per block (2 rows/thread)
#define TB 64            // b-tile per block (4 cols/thread)
#define CH 64            // k-chunk in floats
#define CH4 (CH/4)       // 16 float4 per row-chunk
#define XST 17           // xs stride in float4 (pad: consecutive-row reads hit 8 distinct bank-groups)
#define PLANE (BATCH*NOUT)

typedef float v2f __attribute__((ext_vector_type(2)));

__device__ __forceinline__ float fast_exp2(float v) {
#if __has_builtin(__builtin_amdgcn_exp2f)
  return __builtin_amdgcn_exp2f(v);
#else
  return exp2f(v);
#endif
}
__device__ __forceinline__ float fast_rcp(float v) {
#if __has_builtin(__builtin_amdgcn_rcpf)
  return __builtin_amdgcn_rcpf(v);
#else
  return 1.0f / v;
#endif
}

// Sum of 4 sigmoids, ONE rcp, packed-FP32 friendly.
// p_i = -log2e * x*w (x pre-scaled); e_i = 2^{p_i}; A_i = 1+e_i.
// sum 1/A_i = ((A+B)*CD + (C+D)*AB) / (AB*CD); pairs as [A,C],[B,D].
__device__ __forceinline__ float sig4(v2f p02, v2f p13) {
  float e0 = fast_exp2(p02.x), e2 = fast_exp2(p02.y);
  float e1 = fast_exp2(p13.x), e3 = fast_exp2(p13.y);
  v2f f02 = {e0, e2}; f02 += 1.0f;
  v2f f13 = {e1, e3}; f13 += 1.0f;
  v2f prod = f02 * f13;                                    // [AB, CD]
  v2f sum  = f02 + f13;                                    // [A+B, C+D]
  v2f prodsw = __builtin_shufflevector(prod, prod, 1, 0);  // [CD, AB]
  v2f t = sum * prodsw;
  return (t.x + t.y) * fast_rcp(prod.x * prod.y);
}

// Kernel A: part[z][i][b] = prod_{j range} sum_{k chunks} sigmoid(x*w)
// 32x64 tile, 2x4 per thread: 6 b128 LDS reads serve 32 sigmoids (3 B/sig).
// Main path JPB=KCB=1: grid 4x4x64 = 1024 blocks, 24.7 KB LDS, 4 resident/CU.
template<int JPB, int KCB>
__global__ __launch_bounds__(THREADS, 4) void dnm_partial_kernel(
    const float* __restrict__ x, const float* __restrict__ w,
    float* __restrict__ part)
{
  __shared__ float4 xs4[TI * XST];     // stride-17 padded
  __shared__ float4 ws4[TB * CH4];     // XOR-swizzled by (row>>2)&7

  const int t  = threadIdx.x;
  const int ti = t >> 4;      // 0..15 -> i rows i0+2*ti, +1
  const int n  = t & 15;      // 0..15 -> b cols b0+4*n .. +3
  const int b0 = blockIdx.x * TB;
  const int i0 = blockIdx.y * TI;
  constexpr int KG = (IN / CH) / KCB;
  const int j0 = (blockIdx.z / KG) * JPB;
  const int q0 = (blockIdx.z % KG) * KCB;

  const float4* gx = (const float4*)x;
  const float4* gw = (const float4*)w;
  const float NEG_LOG2E = -1.4426950408889634f;

  float p00=1.f,p01=1.f,p02_=1.f,p03=1.f, p10=1.f,p11=1.f,p12=1.f,p13_=1.f;
  #pragma unroll
  for (int jj = 0; jj < JPB; ++jj) {
    const int j = j0 + jj;
    float s00=0.f,s01=0.f,s02=0.f,s03=0.f, s10=0.f,s11=0.f,s12=0.f,s13=0.f;
    #pragma unroll
    for (int cc = 0; cc < KCB; ++cc) {
      const int q = q0 + cc;
      __syncthreads();
      // stage 96 rows x 16 float4: p=0,1 -> x rows (wave-uniform), p=2..5 -> w rows
      #pragma unroll
      for (int p = 0; p < (TI + TB) * CH4 / THREADS; ++p) {
        int idx = t + p * THREADS;
        int r = idx >> 4, c4 = idx & 15;
        if (r < TI) {
          float4 xv = gx[(size_t)((i0 + r) * MB + j) * (IN / 4) + q * CH4 + c4];
          xv.x *= NEG_LOG2E; xv.y *= NEG_LOG2E; xv.z *= NEG_LOG2E; xv.w *= NEG_LOG2E;
          xs4[r * XST + c4] = xv;
        } else {
          int rw = r - TI;                       // 0..63
          int c4s = c4 ^ ((rw >> 2) & 7);        // XOR swizzle
          ws4[rw * CH4 + c4s] = gw[(size_t)((b0 + rw) * MB + j) * (IN / 4) + q * CH4 + c4];
        }
      }
      __syncthreads();
      const float4* __restrict__ xr0 = &xs4[(2 * ti)     * XST];
      const float4* __restrict__ xr1 = &xs4[(2 * ti + 1) * XST];
      const float4* __restrict__ wr  = &ws4[(4 * n) * CH4];
      const int sw = n & 7;                      // (4n+c)>>2 == n for c<4
      #pragma unroll 4
      for (int k4 = 0; k4 < CH4; ++k4) {
        float4 xv0 = xr0[k4], xv1 = xr1[k4];     // 8 unique rows/wave, 8 bank-groups: conflict-free
        int kw = k4 ^ sw;                        // 16 addrs on 8 groups: 2-way = free
        float4 wv0 = wr[0 * CH4 + kw];
        float4 wv1 = wr[1 * CH4 + kw];
        float4 wv2 = wr[2 * CH4 + kw];
        float4 wv3 = wr[3 * CH4 + kw];
        v2f x0a = {xv0.x, xv0.z}, x0b = {xv0.y, xv0.w};
        v2f x1a = {xv1.x, xv1.z}, x1b = {xv1.y, xv1.w};
        v2f wa, wb;
        wa = (v2f){wv0.x, wv0.z}; wb = (v2f){wv0.y, wv0.w};
        s00 += sig4(x0a * wa, x0b * wb);
        s10 += sig4(x1a * wa, x1b * wb);
        wa = (v2f){wv1.x, wv1.z}; wb = (v2f){wv1.y, wv1.w};
        s01 += sig4(x0a * wa, x0b * wb);
        s11 += sig4(x1a * wa, x1b * wb);
        wa = (v2f){wv2.x, wv2.z}; wb = (v2f){wv2.y, wv2.w};
        s02 += sig4(x0a * wa, x0b * wb);
        s12 += sig4(x1a * wa, x1b * wb);
        wa = (v2f){wv3.x, wv3.z}; wb = (v2f){wv3.y, wv3.w};
        s03 += sig4(x0a * wa, x0b * wb);
        s13 += sig4(x1a * wa, x1b * wb);
      }
    }
    p00 *= s00; p01 *= s01; p02_ *= s02; p03 *= s03;
    p10 *= s10; p11 *= s11; p12 *= s12; p13_ *= s13;
  }
  float4* dst = (float4*)(part + (size_t)blockIdx.z * PLANE);
  const int i = i0 + 2 * ti, bq = (b0 >> 2) + n;   // float4 col index
  dst[(size_t)i * (NOUT / 4) + bq]       = make_float4(p00, p01, p02_, p03);
  dst[(size_t)(i + 1) * (NOUT / 4) + bq] = make_float4(p10, p11, p12, p13_);
}

__device__ __forceinline__ float block_sum(float v, float* red) {
  #pragma unroll
  for (int o = 32; o > 0; o >>= 1) v += __shfl_down(v, o, 64);
  int lane = threadIdx.x & 63, wid = threadIdx.x >> 6;
  __syncthreads();
  if (lane == 0) red[wid] = v;
  __syncthreads();
  return red[0] + red[1] + red[2] + red[3];
}

// Kernel B: z[i][b] = prod_j sum_q part[j*KG+q][i][b]; row-normalize + standardize (ddof=1)
template<int JG, int KG>
__global__ __launch_bounds__(256) void dnm_norm_kernel(
    const float* __restrict__ part, float* __restrict__ out)
{
  __shared__ float red[4];
  const int i = blockIdx.x;
  const int t = threadIdx.x;
  float z = 1.0f;
  #pragma unroll
  for (int j = 0; j < JG; ++j) {
    float s = 0.0f;
    #pragma unroll
    for (int q = 0; q < KG; ++q)
      s += part[(size_t)(j * KG + q) * PLANE + (size_t)i * NOUT + t];
    z *= s;
  }
  float S  = block_sum(z, red);
  float zn = z / S;
  float m  = block_sum(zn, red) * (1.0f / NOUT);
  float dv = zn - m;
  float v  = block_sum(dv * dv, red) * (1.0f / (NOUT - 1));
  out[(size_t)i * NOUT + t] = dv / sqrtf(v);
}

extern "C" void kernel_launch(void* const* d_in, const int* in_sizes, int n_in,
                              void* d_out, int out_size, void* d_ws, size_t ws_size,
                              hipStream_t stream) {
  const float* x = (const float*)d_in[0];   // (128, 8, 512)
  const float* w = (const float*)d_in[1];   // (256, 8, 512)
  float* out = (float*)d_out;               // (128, 256)

  const size_t plane_bytes = (size_t)PLANE * sizeof(float);

  if (ws_size >= 64 * plane_bytes) {
    // Main path: jg=8 x kg=8 -> 1024 blocks.
    float* part = (float*)d_ws;
    dim3 gridA(NOUT / TB, BATCH / TI, 64);
    dnm_partial_kernel<1, 1><<<gridA, THREADS, 0, stream>>>(x, w, part);
    dnm_norm_kernel<8, 8><<<dim3(BATCH), 256, 0, stream>>>(part, out);
  } else if (ws_size >= plane_bytes) {
    float* part = (float*)d_ws;
    dim3 gridA(NOUT / TB, BATCH / TI, 1);
    dnm_partial_kernel<8, 8><<<gridA, THREADS, 0, stream>>>(x, w, part);
    dnm_norm_kernel<1, 1><<<dim3(BATCH), 256, 0, stream>>>(part, out);
  } else {
    float* part = out;                        // in-place fallback
    dim3 gridA(NOUT / TB, BATCH / TI, 1);
    dnm_partial_kernel<8, 8><<<gridA, THREADS, 0, stream>>>(x, w, part);
    dnm_norm_kernel<1, 1><<<dim3(BATCH), 256, 0, stream>>>(part, out);
  }
}